// Round 2
// baseline (869.562 us; speedup 1.0000x reference)
//
#include <hip/hip_runtime.h>

typedef unsigned short u16;
typedef unsigned int u32;
typedef __attribute__((ext_vector_type(8))) short sh8;
typedef __attribute__((ext_vector_type(4))) float f32x4;
typedef __attribute__((ext_vector_type(2))) float f32x2;

__device__ __forceinline__ float bf2f(u16 u) {
  union { u32 i; float f; } x; x.i = ((u32)u) << 16; return x.f;
}
__device__ __forceinline__ u16 f2bf(float f) {
  union { float f; u32 i; } x; x.f = f;
  u32 u = x.i;
  u32 r = (u + 0x7FFFu + ((u >> 16) & 1u)) >> 16;
  return (u16)r;
}

// MODE: 0 = external tensors are bf16, 1 = external tensors are float32.
template <int MODE>
__device__ __forceinline__ float lds1(const void* p, size_t off) {
  if constexpr (MODE == 0) return bf2f(((const u16*)p)[off]);
  else return ((const float*)p)[off];
}

template <int MODE>
__device__ __forceinline__ sh8 load8(const void* p, size_t off) {
  if constexpr (MODE == 0) {
    return *(const sh8*)((const u16*)p + off);
  } else {
    const float* f = (const float*)p + off;
    f32x4 x = *(const f32x4*)f;
    f32x4 y = *(const f32x4*)(f + 4);
    sh8 r;
    r[0] = (short)f2bf(x[0]); r[1] = (short)f2bf(x[1]);
    r[2] = (short)f2bf(x[2]); r[3] = (short)f2bf(x[3]);
    r[4] = (short)f2bf(y[0]); r[5] = (short)f2bf(y[1]);
    r[6] = (short)f2bf(y[2]); r[7] = (short)f2bf(y[3]);
    return r;
  }
}

// ---------------- dtype detection ----------------
// bf16 randn data never has exponent field 0xFF; f32 data read as u16 has
// uniform low-mantissa halves -> ~1/256 of them do. Count over 64K samples.
__global__ void k_detect(const u16* __restrict__ h, const u16* __restrict__ ctx,
                         int* __restrict__ flag) {
  __shared__ int c;
  if (threadIdx.x == 0) c = 0;
  __syncthreads();
  int local = 0;
  for (int i = threadIdx.x; i < 32768; i += 256) {
    if ((h[i] & 0x7F80) == 0x7F80) local++;
    if ((ctx[i] & 0x7F80) == 0x7F80) local++;
  }
  atomicAdd(&c, local);
  __syncthreads();
  if (threadIdx.x == 0) *flag = (c >= 4) ? 1 : 0;
}

// ---------------- prep: internal bf16 weights (transposed + fused) ----------------
template <int MODE>
__global__ void k_prep(const int* __restrict__ flag,
                       const void* __restrict__ Ws, const void* __restrict__ Wn,
                       const void* __restrict__ Wm, const void* __restrict__ Wg,
                       const void* __restrict__ b_sage, const void* __restrict__ bg,
                       const void* __restrict__ bm, const void* __restrict__ ln_g,
                       const void* __restrict__ ln_b,
                       u16* __restrict__ WmT, u16* __restrict__ WsT, u16* __restrict__ WnT,
                       u16* __restrict__ WsgT, u16* __restrict__ WngT, u16* __restrict__ WgBT,
                       float* __restrict__ bm_f, float* __restrict__ lng_f,
                       float* __restrict__ lnb_f, float* __restrict__ bsage_f,
                       float* __restrict__ bsg) {
  if (*flag != MODE) return;
  int idx = blockIdx.x * blockDim.x + threadIdx.x;
  int stride = gridDim.x * blockDim.x;
  for (int i = idx; i < 32768; i += stride) {
    int n = i >> 8, k = i & 255;
    WmT[n * 256 + k] = f2bf(lds1<MODE>(Wm, k * 128 + n));
  }
  for (int i = idx; i < 16384; i += stride) {
    int n = i >> 7, k = i & 127;
    WsT[i] = f2bf(lds1<MODE>(Ws, k * 128 + n));
    WnT[i] = f2bf(lds1<MODE>(Wn, k * 128 + n));
    WgBT[i] = f2bf(lds1<MODE>(Wg, (128 + k) * 128 + n));
  }
  for (int i = idx; i < 16384; i += stride) {
    int c = i >> 7, k = i & 127;
    float s1 = 0.f, s2 = 0.f;
    for (int j = 0; j < 128; ++j) {
      float wg = lds1<MODE>(Wg, j * 128 + c);
      s1 += lds1<MODE>(Ws, k * 128 + j) * wg;
      s2 += lds1<MODE>(Wn, k * 128 + j) * wg;
    }
    WsgT[c * 128 + k] = f2bf(s1);
    WngT[c * 128 + k] = f2bf(s2);
  }
  for (int i = idx; i < 128; i += stride) {
    bm_f[i] = lds1<MODE>(bm, i);
    lng_f[i] = lds1<MODE>(ln_g, i);
    lnb_f[i] = lds1<MODE>(ln_b, i);
    bsage_f[i] = lds1<MODE>(b_sage, i);
    float s = lds1<MODE>(bg, i);
    for (int j = 0; j < 128; ++j) s += lds1<MODE>(b_sage, j) * lds1<MODE>(Wg, j * 128 + i);
    bsg[i] = s;
  }
}

// ---------------- CSR build (dtype-independent) ----------------
__global__ void k_count(const int* __restrict__ dst, int* __restrict__ cnt, int E) {
  int e = blockIdx.x * blockDim.x + threadIdx.x;
  if (e < E) atomicAdd(&cnt[dst[e]], 1);
}

__global__ void k_scan(const int* __restrict__ cnt, int* __restrict__ rowptr,
                       int* __restrict__ cursor, int N) {
  __shared__ int sdata[1024];
  int t = threadIdx.x;
  int chunk = (N + 1023) >> 10;
  int beg = t * chunk;
  int end = min(beg + chunk, N);
  int s = 0;
  for (int i = beg; i < end; ++i) s += cnt[i];
  sdata[t] = s;
  __syncthreads();
  for (int off = 1; off < 1024; off <<= 1) {
    int v = (t >= off) ? sdata[t - off] : 0;
    __syncthreads();
    sdata[t] += v;
    __syncthreads();
  }
  int excl = sdata[t] - s;
  for (int i = beg; i < end; ++i) {
    rowptr[i] = excl;
    cursor[i] = excl;
    excl += cnt[i];
  }
  if (t == 1023) rowptr[N] = sdata[1023];
}

__global__ void k_perm(const int* __restrict__ src, const int* __restrict__ dst,
                       int* __restrict__ cursor, int* __restrict__ src_sorted, int E) {
  int e = blockIdx.x * blockDim.x + threadIdx.x;
  if (e < E) {
    int p = atomicAdd(&cursor[dst[e]], 1);
    src_sorted[p] = src[e];
  }
}

// ---------------- edge MLP + LayerNorm + ReLU (MFMA 16x16x32 bf16) ----------------
template <int MODE>
__global__ __launch_bounds__(512) void k_edges(
    const int* __restrict__ flag,
    const void* __restrict__ h, const void* __restrict__ ctx,
    const int* __restrict__ src_sorted,
    const u16* __restrict__ WmT, const float* __restrict__ bm_f,
    const float* __restrict__ lng_f, const float* __restrict__ lnb_f,
    u16* __restrict__ msg, int E) {
  if (*flag != MODE) return;
  __shared__ u16 wlds[128 * 256];  // 64 KB: WmT with XOR-swizzled 16B chunks
  int tid = threadIdx.x;
  for (int it = 0; it < 8; ++it) {
    int f = tid + it * 512;
    int n = f >> 5;
    int kc = f & 31;
    int kcs = kc ^ (n & 7);
    *(sh8*)&wlds[n * 256 + kcs * 8] = *(const sh8*)&WmT[n * 256 + kc * 8];
  }
  __syncthreads();
  int lane = tid & 63;
  int wave = tid >> 6;
  int col = lane & 15;
  int quad = lane >> 4;
  float bmv[8], gv[8], bv[8];
#pragma unroll
  for (int t = 0; t < 8; ++t) {
    int c = t * 16 + col;
    bmv[t] = bm_f[c];
    gv[t] = lng_f[c];
    bv[t] = lnb_f[c];
  }
  int totalWaves = gridDim.x * 8;
  int TT = (E + 15) >> 4;
  for (int tile = blockIdx.x * 8 + wave; tile < TT; tile += totalWaves) {
    int pos = tile * 16 + col;  // A-operand row m = lane&15
    int s = src_sorted[min(pos, E - 1)];
    f32x4 acc[8];
#pragma unroll
    for (int t = 0; t < 8; ++t) acc[t] = (f32x4)0.0f;
#pragma unroll
    for (int ks = 0; ks < 8; ++ks) {
      int k = ks * 32 + quad * 8;  // A[m][k..k+7]; never straddles h|ctx seam
      sh8 a = (k < 128) ? load8<MODE>(h, (size_t)s * 128 + k)
                        : load8<MODE>(ctx, (size_t)s * 128 + k - 128);
#pragma unroll
      for (int t = 0; t < 8; ++t) {
        int n = t * 16 + col;
        int kc = ks * 4 + quad;
        int kcs = kc ^ (n & 7);
        sh8 b = *(const sh8*)&wlds[n * 256 + kcs * 8];
        acc[t] = __builtin_amdgcn_mfma_f32_16x16x32_bf16(a, b, acc[t], 0, 0, 0);
      }
    }
    // C/D layout: row = quad*4 + r, col = t*16 + (lane&15). LayerNorm per row.
#pragma unroll
    for (int r = 0; r < 4; ++r) {
      float v[8];
      float s1 = 0.f, s2 = 0.f;
#pragma unroll
      for (int t = 0; t < 8; ++t) {
        v[t] = acc[t][r] + bmv[t];
        s1 += v[t];
        s2 += v[t] * v[t];
      }
#pragma unroll
      for (int m = 1; m < 16; m <<= 1) {
        s1 += __shfl_xor(s1, m, 64);
        s2 += __shfl_xor(s2, m, 64);
      }
      float mu = s1 * (1.f / 128.f);
      float var = s2 * (1.f / 128.f) - mu * mu;
      float rstd = rsqrtf(fmaxf(var, 0.f) + 1e-5f);
      int row = tile * 16 + quad * 4 + r;
      if (row < E) {
        u16* orow = msg + (size_t)row * 128;
#pragma unroll
        for (int t = 0; t < 8; ++t) {
          float x = (v[t] - mu) * rstd * gv[t] + bv[t];
          x = x > 0.f ? x : 0.f;
          orow[t * 16 + col] = f2bf(x);
        }
      }
    }
  }
}

// ---------------- per-node aggregation: neigh_mean + conv_agg ----------------
template <int MODE>
__global__ __launch_bounds__(256) void k_agg(
    const int* __restrict__ flag,
    const void* __restrict__ h, const int* __restrict__ rowptr,
    const int* __restrict__ src_sorted, const u16* __restrict__ msg,
    u16* __restrict__ nm, u16* __restrict__ cagg, int N) {
  if (*flag != MODE) return;
  int gw = (blockIdx.x * 256 + threadIdx.x) >> 6;
  int lane = threadIdx.x & 63;
  int tw = (gridDim.x * 256) >> 6;
  for (int n = gw; n < N; n += tw) {
    int b = rowptr[n], e = rowptr[n + 1];
    float m0 = 0.f, m1 = 0.f, a0 = 0.f, a1 = 0.f;
    for (int i = b; i < e; ++i) {
      u32 vm = *(const u32*)(msg + (size_t)i * 128 + (lane << 1));
      int s = src_sorted[i];
      m0 += bf2f((u16)vm);
      m1 += bf2f((u16)(vm >> 16));
      if constexpr (MODE == 0) {
        u32 vh = *(const u32*)((const u16*)h + (size_t)s * 128 + (lane << 1));
        a0 += bf2f((u16)vh);
        a1 += bf2f((u16)(vh >> 16));
      } else {
        f32x2 vh = *(const f32x2*)((const float*)h + (size_t)s * 128 + (lane << 1));
        a0 += vh[0];
        a1 += vh[1];
      }
    }
    float inv = (e > b) ? 1.f / (float)(e - b) : 0.f;
    u32 pm = (u32)f2bf(m0 * inv) | ((u32)f2bf(m1 * inv) << 16);
    u32 pa = (u32)f2bf(a0 * inv) | ((u32)f2bf(a1 * inv) << 16);
    *(u32*)(cagg + (size_t)n * 128 + (lane << 1)) = pm;
    *(u32*)(nm + (size_t)n * 128 + (lane << 1)) = pa;
  }
}

// ---------------- fused node GEMMs + gate + blend ----------------
template <int MODE>
__global__ __launch_bounds__(256) void k_out(
    const int* __restrict__ flag,
    const void* __restrict__ h, const u16* __restrict__ nm, const u16* __restrict__ cagg,
    const u16* __restrict__ WsT, const u16* __restrict__ WnT,
    const u16* __restrict__ WsgT, const u16* __restrict__ WngT, const u16* __restrict__ WgBT,
    const float* __restrict__ bsage_f, const float* __restrict__ bsg,
    void* __restrict__ out, int N) {
  if (*flag != MODE) return;
  int gw = (blockIdx.x * 256 + threadIdx.x) >> 6;
  int lane = threadIdx.x & 63;
  int tw = (gridDim.x * 256) >> 6;
  int col = lane & 15, quad = lane >> 4;
  float bsv[8], bgv[8];
#pragma unroll
  for (int t = 0; t < 8; ++t) {
    bsv[t] = bsage_f[t * 16 + col];
    bgv[t] = bsg[t * 16 + col];
  }
  int TT = (N + 15) >> 4;
  for (int tile = gw; tile < TT; tile += tw) {
    int n0 = tile * 16;
    int nr = min(n0 + col, N - 1);
    sh8 ah[4], am[4], ac[4];
#pragma unroll
    for (int ks = 0; ks < 4; ++ks) {
      int k = ks * 32 + quad * 8;
      ah[ks] = load8<MODE>(h, (size_t)nr * 128 + k);
      am[ks] = *(const sh8*)&nm[(size_t)nr * 128 + k];
      ac[ks] = *(const sh8*)&cagg[(size_t)nr * 128 + k];
    }
    f32x4 as[8], ag[8];
#pragma unroll
    for (int t = 0; t < 8; ++t) {
      as[t] = (f32x4)0.0f;
      ag[t] = (f32x4)0.0f;
    }
#pragma unroll
    for (int ks = 0; ks < 4; ++ks) {
      int k = ks * 32 + quad * 8;
#pragma unroll
      for (int t = 0; t < 8; ++t) {
        int bo = (t * 16 + col) * 128 + k;
        sh8 b1 = *(const sh8*)&WsT[bo];
        sh8 b2 = *(const sh8*)&WnT[bo];
        sh8 b3 = *(const sh8*)&WsgT[bo];
        sh8 b4 = *(const sh8*)&WngT[bo];
        sh8 b5 = *(const sh8*)&WgBT[bo];
        as[t] = __builtin_amdgcn_mfma_f32_16x16x32_bf16(ah[ks], b1, as[t], 0, 0, 0);
        as[t] = __builtin_amdgcn_mfma_f32_16x16x32_bf16(am[ks], b2, as[t], 0, 0, 0);
        ag[t] = __builtin_amdgcn_mfma_f32_16x16x32_bf16(ah[ks], b3, ag[t], 0, 0, 0);
        ag[t] = __builtin_amdgcn_mfma_f32_16x16x32_bf16(am[ks], b4, ag[t], 0, 0, 0);
        ag[t] = __builtin_amdgcn_mfma_f32_16x16x32_bf16(ac[ks], b5, ag[t], 0, 0, 0);
      }
    }
#pragma unroll
    for (int r = 0; r < 4; ++r) {
      int n = n0 + quad * 4 + r;
      if (n < N) {
        const u16* crow = cagg + (size_t)n * 128;
#pragma unroll
        for (int t = 0; t < 8; ++t) {
          float sv = as[t][r] + bsv[t];
          float gl = ag[t][r] + bgv[t];
          float g = 1.f / (1.f + __expf(-gl));
          float ca = bf2f(crow[t * 16 + col]);
          float o = g * sv + (1.f - g) * ca;
          if constexpr (MODE == 0)
            ((u16*)out)[(size_t)n * 128 + t * 16 + col] = f2bf(o);
          else
            ((float*)out)[(size_t)n * 128 + t * 16 + col] = o;
        }
      }
    }
  }
}

extern "C" void kernel_launch(void* const* d_in, const int* in_sizes, int n_in,
                              void* d_out, int out_size, void* d_ws, size_t ws_size,
                              hipStream_t stream) {
  const void* h = d_in[0];
  const void* ctx = d_in[1];
  const int* src = (const int*)d_in[2];
  const int* dst = (const int*)d_in[3];
  const void* Ws = d_in[4];
  const void* Wn = d_in[5];
  const void* b_sage = d_in[6];
  const void* Wm = d_in[7];
  const void* bm = d_in[8];
  const void* ln_g = d_in[9];
  const void* ln_b = d_in[10];
  const void* Wg = d_in[11];
  const void* bg = d_in[12];
  int N = in_sizes[0] / 128;
  int E = in_sizes[2];

  char* w = (char*)d_ws;
  auto carve = [&](size_t bytes) {
    char* p = w;
    w += (bytes + 255) & ~(size_t)255;
    return p;
  };
  int* flag = (int*)carve(4);
  int* cnt = (int*)carve((size_t)N * 4);
  int* rowptr = (int*)carve((size_t)(N + 1) * 4);
  int* cursor = (int*)carve((size_t)N * 4);
  int* src_sorted = (int*)carve((size_t)E * 4);
  u16* WmT = (u16*)carve(32768 * 2);
  u16* WsT = (u16*)carve(16384 * 2);
  u16* WnT = (u16*)carve(16384 * 2);
  u16* WsgT = (u16*)carve(16384 * 2);
  u16* WngT = (u16*)carve(16384 * 2);
  u16* WgBT = (u16*)carve(16384 * 2);
  float* bm_f = (float*)carve(128 * 4);
  float* lng_f = (float*)carve(128 * 4);
  float* lnb_f = (float*)carve(128 * 4);
  float* bsage_f = (float*)carve(128 * 4);
  float* bsg = (float*)carve(128 * 4);
  u16* nm = (u16*)carve((size_t)N * 128 * 2);
  u16* cagg = (u16*)carve((size_t)N * 128 * 2);
  u16* msg = (u16*)carve((size_t)E * 128 * 2);

  hipMemsetAsync(cnt, 0, (size_t)N * 4, stream);
  k_detect<<<1, 256, 0, stream>>>((const u16*)h, (const u16*)ctx, flag);
  k_prep<0><<<128, 256, 0, stream>>>(flag, Ws, Wn, Wm, Wg, b_sage, bg, bm, ln_g, ln_b,
                                     WmT, WsT, WnT, WsgT, WngT, WgBT,
                                     bm_f, lng_f, lnb_f, bsage_f, bsg);
  k_prep<1><<<128, 256, 0, stream>>>(flag, Ws, Wn, Wm, Wg, b_sage, bg, bm, ln_g, ln_b,
                                     WmT, WsT, WnT, WsgT, WngT, WgBT,
                                     bm_f, lng_f, lnb_f, bsage_f, bsg);
  k_count<<<(E + 255) / 256, 256, 0, stream>>>(dst, cnt, E);
  k_scan<<<1, 1024, 0, stream>>>(cnt, rowptr, cursor, N);
  k_perm<<<(E + 255) / 256, 256, 0, stream>>>(src, dst, cursor, src_sorted, E);
  k_edges<0><<<512, 512, 0, stream>>>(flag, h, ctx, src_sorted, WmT, bm_f, lng_f, lnb_f,
                                      msg, E);
  k_edges<1><<<512, 512, 0, stream>>>(flag, h, ctx, src_sorted, WmT, bm_f, lng_f, lnb_f,
                                      msg, E);
  k_agg<0><<<1024, 256, 0, stream>>>(flag, h, rowptr, src_sorted, msg, nm, cagg, N);
  k_agg<1><<<1024, 256, 0, stream>>>(flag, h, rowptr, src_sorted, msg, nm, cagg, N);
  k_out<0><<<512, 256, 0, stream>>>(flag, h, nm, cagg, WsT, WnT, WsgT, WngT, WgBT,
                                    bsage_f, bsg, d_out, N);
  k_out<1><<<512, 256, 0, stream>>>(flag, h, nm, cagg, WsT, WnT, WsgT, WngT, WgBT,
                                    bsage_f, bsg, d_out, N);
}

// Round 3
// 600.365 us; speedup vs baseline: 1.4484x; 1.4484x over previous
//
#include <hip/hip_runtime.h>

typedef unsigned short u16;
typedef unsigned int u32;
typedef __attribute__((ext_vector_type(8))) short sh8;
typedef __attribute__((ext_vector_type(4))) float f32x4;
typedef __attribute__((ext_vector_type(4))) unsigned short us4;

__device__ __forceinline__ float bf2f(u16 u) {
  union { u32 i; float f; } x; x.i = ((u32)u) << 16; return x.f;
}
__device__ __forceinline__ u16 f2bf(float f) {
  union { float f; u32 i; } x; x.f = f;
  u32 u = x.i;
  u32 r = (u + 0x7FFFu + ((u >> 16) & 1u)) >> 16;
  return (u16)r;
}

// MODE: 0 = external tensors are bf16, 1 = external tensors are float32.
template <int MODE>
__device__ __forceinline__ float lds1(const void* p, size_t off) {
  if constexpr (MODE == 0) return bf2f(((const u16*)p)[off]);
  else return ((const float*)p)[off];
}

template <int MODE>
__device__ __forceinline__ sh8 load8(const void* p, size_t off) {
  if constexpr (MODE == 0) {
    return *(const sh8*)((const u16*)p + off);
  } else {
    const float* f = (const float*)p + off;
    f32x4 x = *(const f32x4*)f;
    f32x4 y = *(const f32x4*)(f + 4);
    sh8 r;
    r[0] = (short)f2bf(x[0]); r[1] = (short)f2bf(x[1]);
    r[2] = (short)f2bf(x[2]); r[3] = (short)f2bf(x[3]);
    r[4] = (short)f2bf(y[0]); r[5] = (short)f2bf(y[1]);
    r[6] = (short)f2bf(y[2]); r[7] = (short)f2bf(y[3]);
    return r;
  }
}

// ---------------- dtype detection (f32 mantissa halves hit exp==0xFF) -------
__global__ void k_detect(const u16* __restrict__ h, const u16* __restrict__ ctx,
                         int* __restrict__ flag) {
  __shared__ int c;
  if (threadIdx.x == 0) c = 0;
  __syncthreads();
  int local = 0;
  for (int i = threadIdx.x; i < 32768; i += 256) {
    if ((h[i] & 0x7F80) == 0x7F80) local++;
    if ((ctx[i] & 0x7F80) == 0x7F80) local++;
  }
  atomicAdd(&c, local);
  __syncthreads();
  if (threadIdx.x == 0) *flag = (c >= 4) ? 1 : 0;
}

// ---------------- prep: internal bf16 weights (transposed + fused) ----------
template <int MODE>
__global__ void k_prep(const int* __restrict__ flag,
                       const void* __restrict__ Ws, const void* __restrict__ Wn,
                       const void* __restrict__ Wm, const void* __restrict__ Wg,
                       const void* __restrict__ b_sage, const void* __restrict__ bg,
                       const void* __restrict__ bm, const void* __restrict__ ln_g,
                       const void* __restrict__ ln_b,
                       u16* __restrict__ WmT, u16* __restrict__ WsT, u16* __restrict__ WnT,
                       u16* __restrict__ WsgT, u16* __restrict__ WngT, u16* __restrict__ WgBT,
                       float* __restrict__ bm_f, float* __restrict__ lng_f,
                       float* __restrict__ lnb_f, float* __restrict__ bsage_f,
                       float* __restrict__ bsg) {
  if (*flag != MODE) return;
  int idx = blockIdx.x * blockDim.x + threadIdx.x;
  int stride = gridDim.x * blockDim.x;
  for (int i = idx; i < 32768; i += stride) {
    int n = i >> 8, k = i & 255;
    WmT[n * 256 + k] = f2bf(lds1<MODE>(Wm, k * 128 + n));
  }
  for (int i = idx; i < 16384; i += stride) {
    int n = i >> 7, k = i & 127;
    WsT[i] = f2bf(lds1<MODE>(Ws, k * 128 + n));
    WnT[i] = f2bf(lds1<MODE>(Wn, k * 128 + n));
    WgBT[i] = f2bf(lds1<MODE>(Wg, (128 + k) * 128 + n));
  }
  for (int i = idx; i < 16384; i += stride) {
    int c = i >> 7, k = i & 127;
    float s1 = 0.f, s2 = 0.f;
    for (int j = 0; j < 128; ++j) {
      float wg = lds1<MODE>(Wg, j * 128 + c);
      s1 += lds1<MODE>(Ws, k * 128 + j) * wg;
      s2 += lds1<MODE>(Wn, k * 128 + j) * wg;
    }
    WsgT[c * 128 + k] = f2bf(s1);
    WngT[c * 128 + k] = f2bf(s2);
  }
  for (int i = idx; i < 128; i += stride) {
    bm_f[i] = lds1<MODE>(bm, i);
    lng_f[i] = lds1<MODE>(ln_g, i);
    lnb_f[i] = lds1<MODE>(ln_b, i);
    bsage_f[i] = lds1<MODE>(b_sage, i);
    float s = lds1<MODE>(bg, i);
    for (int j = 0; j < 128; ++j) s += lds1<MODE>(b_sage, j) * lds1<MODE>(Wg, j * 128 + i);
    bsg[i] = s;
  }
}

// ---------------- CSR build ----------------
__global__ void k_count(const int* __restrict__ dst, int* __restrict__ cnt, int E) {
  int e = blockIdx.x * blockDim.x + threadIdx.x;
  if (e < E) atomicAdd(&cnt[dst[e]], 1);
}

__global__ void k_scan(const int* __restrict__ cnt, int* __restrict__ rowptr,
                       int* __restrict__ cursor, int N) {
  __shared__ int sdata[1024];
  int t = threadIdx.x;
  int chunk = (N + 1023) >> 10;
  int beg = t * chunk;
  int end = min(beg + chunk, N);
  int s = 0;
  for (int i = beg; i < end; ++i) s += cnt[i];
  sdata[t] = s;
  __syncthreads();
  for (int off = 1; off < 1024; off <<= 1) {
    int v = (t >= off) ? sdata[t - off] : 0;
    __syncthreads();
    sdata[t] += v;
    __syncthreads();
  }
  int excl = sdata[t] - s;
  for (int i = beg; i < end; ++i) {
    rowptr[i] = excl;
    cursor[i] = excl;
    excl += cnt[i];
  }
  if (t == 1023) rowptr[N] = sdata[1023];
}

__global__ void k_perm(const int* __restrict__ src, const int* __restrict__ dst,
                       int* __restrict__ cursor, int* __restrict__ src_sorted, int E) {
  int e = blockIdx.x * blockDim.x + threadIdx.x;
  if (e < E) {
    int p = atomicAdd(&cursor[dst[e]], 1);
    src_sorted[p] = src[e];
  }
}

// ---------------- node MLP: M = relu(LN(concat(h,ctx)@Wm + bm)) -------------
// msg_e depends only on src -> compute once per NODE, not per edge (10x less).
// Output interleaved: hm[n][0..127] = bf16(h[n]), hm[n][128..255] = M[n].
template <int MODE>
__global__ __launch_bounds__(512) void k_node(
    const int* __restrict__ flag,
    const void* __restrict__ h, const void* __restrict__ ctx,
    const u16* __restrict__ WmT, const float* __restrict__ bm_f,
    const float* __restrict__ lng_f, const float* __restrict__ lnb_f,
    u16* __restrict__ hm, int N) {
  if (*flag != MODE) return;
  __shared__ u16 wlds[128 * 256];  // 64 KB: WmT, XOR-swizzled 16B chunks
  int tid = threadIdx.x;
  for (int it = 0; it < 8; ++it) {
    int f = tid + it * 512;
    int n = f >> 5;
    int kc = f & 31;
    int kcs = kc ^ (n & 7);
    *(sh8*)&wlds[n * 256 + kcs * 8] = *(const sh8*)&WmT[n * 256 + kc * 8];
  }
  __syncthreads();
  int lane = tid & 63;
  int wave = tid >> 6;
  int col = lane & 15;
  int quad = lane >> 4;
  float bmv[8], gv[8], bv[8];
#pragma unroll
  for (int t = 0; t < 8; ++t) {
    int c = t * 16 + col;
    bmv[t] = bm_f[c];
    gv[t] = lng_f[c];
    bv[t] = lnb_f[c];
  }
  int totalWaves = gridDim.x * 8;
  int TT = (N + 15) >> 4;
  for (int tile = blockIdx.x * 8 + wave; tile < TT; tile += totalWaves) {
    int n0 = tile * 16;
    int m = min(n0 + col, N - 1);  // A row = this node (contiguous, no gather)
    f32x4 acc[8];
    sh8 afrag[4];
#pragma unroll
    for (int t = 0; t < 8; ++t) acc[t] = (f32x4)0.0f;
#pragma unroll
    for (int ks = 0; ks < 8; ++ks) {
      int k = ks * 32 + quad * 8;
      sh8 a = (k < 128) ? load8<MODE>(h, (size_t)m * 128 + k)
                        : load8<MODE>(ctx, (size_t)m * 128 + k - 128);
      if (ks < 4) afrag[ks & 3] = a;
#pragma unroll
      for (int t = 0; t < 8; ++t) {
        int n = t * 16 + col;
        int kc = ks * 4 + quad;
        int kcs = kc ^ (n & 7);
        sh8 b = *(const sh8*)&wlds[n * 256 + kcs * 8];
        acc[t] = __builtin_amdgcn_mfma_f32_16x16x32_bf16(a, b, acc[t], 0, 0, 0);
      }
    }
    // store bf16(h) half straight from the A fragments (16B stores)
#pragma unroll
    for (int ks = 0; ks < 4; ++ks)
      *(sh8*)&hm[(size_t)m * 256 + ks * 32 + quad * 8] = afrag[ks];
    // LayerNorm + ReLU per output row; store M half
#pragma unroll
    for (int r = 0; r < 4; ++r) {
      float v[8];
      float s1 = 0.f, s2 = 0.f;
#pragma unroll
      for (int t = 0; t < 8; ++t) {
        v[t] = acc[t][r] + bmv[t];
        s1 += v[t];
        s2 += v[t] * v[t];
      }
#pragma unroll
      for (int mm = 1; mm < 16; mm <<= 1) {
        s1 += __shfl_xor(s1, mm, 64);
        s2 += __shfl_xor(s2, mm, 64);
      }
      float mu = s1 * (1.f / 128.f);
      float var = s2 * (1.f / 128.f) - mu * mu;
      float rstd = rsqrtf(fmaxf(var, 0.f) + 1e-5f);
      int row = n0 + quad * 4 + r;
      if (row < N) {
        u16* orow = hm + (size_t)row * 256 + 128;
#pragma unroll
        for (int t = 0; t < 8; ++t) {
          float x = (v[t] - mu) * rstd * gv[t] + bv[t];
          x = x > 0.f ? x : 0.f;
          orow[t * 16 + col] = f2bf(x);
        }
      }
    }
  }
}

// ---------------- per-node aggregation over hm rows -------------------------
// One wave per dst node; each edge gathers ONE contiguous 512B hm row that
// serves both neigh_mean (cols 0..127) and conv_agg (cols 128..255).
__global__ __launch_bounds__(256) void k_agg(
    const u16* __restrict__ hm, const int* __restrict__ rowptr,
    const int* __restrict__ src_sorted,
    u16* __restrict__ nm, u16* __restrict__ cagg, int N) {
  int gw = (blockIdx.x * 256 + threadIdx.x) >> 6;
  int lane = threadIdx.x & 63;
  int tw = (gridDim.x * 256) >> 6;
  for (int n = gw; n < N; n += tw) {
    int b = rowptr[n], e = rowptr[n + 1];
    float s0 = 0.f, s1 = 0.f, s2 = 0.f, s3 = 0.f;
    int i = b;
    for (; i + 4 <= e; i += 4) {  // 4 gathers in flight
      int e0 = src_sorted[i], e1 = src_sorted[i + 1];
      int e2 = src_sorted[i + 2], e3 = src_sorted[i + 3];
      us4 v0 = *(const us4*)(hm + (size_t)e0 * 256 + (lane << 2));
      us4 v1 = *(const us4*)(hm + (size_t)e1 * 256 + (lane << 2));
      us4 v2 = *(const us4*)(hm + (size_t)e2 * 256 + (lane << 2));
      us4 v3 = *(const us4*)(hm + (size_t)e3 * 256 + (lane << 2));
      s0 += bf2f(v0[0]) + bf2f(v1[0]) + bf2f(v2[0]) + bf2f(v3[0]);
      s1 += bf2f(v0[1]) + bf2f(v1[1]) + bf2f(v2[1]) + bf2f(v3[1]);
      s2 += bf2f(v0[2]) + bf2f(v1[2]) + bf2f(v2[2]) + bf2f(v3[2]);
      s3 += bf2f(v0[3]) + bf2f(v1[3]) + bf2f(v2[3]) + bf2f(v3[3]);
    }
    for (; i < e; ++i) {
      int e0 = src_sorted[i];
      us4 v0 = *(const us4*)(hm + (size_t)e0 * 256 + (lane << 2));
      s0 += bf2f(v0[0]);
      s1 += bf2f(v0[1]);
      s2 += bf2f(v0[2]);
      s3 += bf2f(v0[3]);
    }
    float inv = (e > b) ? 1.f / (float)(e - b) : 0.f;
    us4 p;
    p[0] = f2bf(s0 * inv); p[1] = f2bf(s1 * inv);
    p[2] = f2bf(s2 * inv); p[3] = f2bf(s3 * inv);
    if (lane < 32)
      *(us4*)(nm + (size_t)n * 128 + (lane << 2)) = p;
    else
      *(us4*)(cagg + (size_t)n * 128 + ((lane - 32) << 2)) = p;
  }
}

// ---------------- fused node GEMMs + gate + blend ----------------
// std  = h@Ws + nm@Wn + b_sage
// gate = sigmoid(h@Wsg + nm@Wng + cagg@WgB + bsg)
// out  = gate*std + (1-gate)*cagg
template <int MODE>
__global__ __launch_bounds__(256) void k_out(
    const int* __restrict__ flag,
    const u16* __restrict__ hm, const u16* __restrict__ nm, const u16* __restrict__ cagg,
    const u16* __restrict__ WsT, const u16* __restrict__ WnT,
    const u16* __restrict__ WsgT, const u16* __restrict__ WngT, const u16* __restrict__ WgBT,
    const float* __restrict__ bsage_f, const float* __restrict__ bsg,
    void* __restrict__ out, int N) {
  if (*flag != MODE) return;
  int gw = (blockIdx.x * 256 + threadIdx.x) >> 6;
  int lane = threadIdx.x & 63;
  int tw = (gridDim.x * 256) >> 6;
  int col = lane & 15, quad = lane >> 4;
  float bsv[8], bgv[8];
#pragma unroll
  for (int t = 0; t < 8; ++t) {
    bsv[t] = bsage_f[t * 16 + col];
    bgv[t] = bsg[t * 16 + col];
  }
  int TT = (N + 15) >> 4;
  for (int tile = gw; tile < TT; tile += tw) {
    int n0 = tile * 16;
    int nr = min(n0 + col, N - 1);
    sh8 ah[4], am[4], ac[4];
#pragma unroll
    for (int ks = 0; ks < 4; ++ks) {
      int k = ks * 32 + quad * 8;
      ah[ks] = *(const sh8*)&hm[(size_t)nr * 256 + k];
      am[ks] = *(const sh8*)&nm[(size_t)nr * 128 + k];
      ac[ks] = *(const sh8*)&cagg[(size_t)nr * 128 + k];
    }
    f32x4 as[8], ag[8];
#pragma unroll
    for (int t = 0; t < 8; ++t) {
      as[t] = (f32x4)0.0f;
      ag[t] = (f32x4)0.0f;
    }
#pragma unroll
    for (int ks = 0; ks < 4; ++ks) {
      int k = ks * 32 + quad * 8;
#pragma unroll
      for (int t = 0; t < 8; ++t) {
        int bo = (t * 16 + col) * 128 + k;
        sh8 b1 = *(const sh8*)&WsT[bo];
        sh8 b2 = *(const sh8*)&WnT[bo];
        sh8 b3 = *(const sh8*)&WsgT[bo];
        sh8 b4 = *(const sh8*)&WngT[bo];
        sh8 b5 = *(const sh8*)&WgBT[bo];
        as[t] = __builtin_amdgcn_mfma_f32_16x16x32_bf16(ah[ks], b1, as[t], 0, 0, 0);
        as[t] = __builtin_amdgcn_mfma_f32_16x16x32_bf16(am[ks], b2, as[t], 0, 0, 0);
        ag[t] = __builtin_amdgcn_mfma_f32_16x16x32_bf16(ah[ks], b3, ag[t], 0, 0, 0);
        ag[t] = __builtin_amdgcn_mfma_f32_16x16x32_bf16(am[ks], b4, ag[t], 0, 0, 0);
        ag[t] = __builtin_amdgcn_mfma_f32_16x16x32_bf16(ac[ks], b5, ag[t], 0, 0, 0);
      }
    }
#pragma unroll
    for (int r = 0; r < 4; ++r) {
      int n = n0 + quad * 4 + r;
      if (n < N) {
        const u16* crow = cagg + (size_t)n * 128;
#pragma unroll
        for (int t = 0; t < 8; ++t) {
          float sv = as[t][r] + bsv[t];
          float gl = ag[t][r] + bgv[t];
          float g = 1.f / (1.f + __expf(-gl));
          float ca = bf2f(crow[t * 16 + col]);
          float o = g * sv + (1.f - g) * ca;
          if constexpr (MODE == 0)
            ((u16*)out)[(size_t)n * 128 + t * 16 + col] = f2bf(o);
          else
            ((float*)out)[(size_t)n * 128 + t * 16 + col] = o;
        }
      }
    }
  }
}

extern "C" void kernel_launch(void* const* d_in, const int* in_sizes, int n_in,
                              void* d_out, int out_size, void* d_ws, size_t ws_size,
                              hipStream_t stream) {
  const void* h = d_in[0];
  const void* ctx = d_in[1];
  const int* src = (const int*)d_in[2];
  const int* dst = (const int*)d_in[3];
  const void* Ws = d_in[4];
  const void* Wn = d_in[5];
  const void* b_sage = d_in[6];
  const void* Wm = d_in[7];
  const void* bm = d_in[8];
  const void* ln_g = d_in[9];
  const void* ln_b = d_in[10];
  const void* Wg = d_in[11];
  const void* bg = d_in[12];
  int N = in_sizes[0] / 128;
  int E = in_sizes[2];

  char* w = (char*)d_ws;
  auto carve = [&](size_t bytes) {
    char* p = w;
    w += (bytes + 255) & ~(size_t)255;
    return p;
  };
  int* flag = (int*)carve(4);
  int* cnt = (int*)carve((size_t)N * 4);
  int* rowptr = (int*)carve((size_t)(N + 1) * 4);
  int* cursor = (int*)carve((size_t)N * 4);
  int* src_sorted = (int*)carve((size_t)E * 4);
  u16* WmT = (u16*)carve(32768 * 2);
  u16* WsT = (u16*)carve(16384 * 2);
  u16* WnT = (u16*)carve(16384 * 2);
  u16* WsgT = (u16*)carve(16384 * 2);
  u16* WngT = (u16*)carve(16384 * 2);
  u16* WgBT = (u16*)carve(16384 * 2);
  float* bm_f = (float*)carve(128 * 4);
  float* lng_f = (float*)carve(128 * 4);
  float* lnb_f = (float*)carve(128 * 4);
  float* bsage_f = (float*)carve(128 * 4);
  float* bsg = (float*)carve(128 * 4);
  u16* hm = (u16*)carve((size_t)N * 256 * 2);
  u16* nm = (u16*)carve((size_t)N * 128 * 2);
  u16* cagg = (u16*)carve((size_t)N * 128 * 2);

  hipMemsetAsync(cnt, 0, (size_t)N * 4, stream);
  k_detect<<<1, 256, 0, stream>>>((const u16*)h, (const u16*)ctx, flag);
  k_prep<0><<<128, 256, 0, stream>>>(flag, Ws, Wn, Wm, Wg, b_sage, bg, bm, ln_g, ln_b,
                                     WmT, WsT, WnT, WsgT, WngT, WgBT,
                                     bm_f, lng_f, lnb_f, bsage_f, bsg);
  k_prep<1><<<128, 256, 0, stream>>>(flag, Ws, Wn, Wm, Wg, b_sage, bg, bm, ln_g, ln_b,
                                     WmT, WsT, WnT, WsgT, WngT, WgBT,
                                     bm_f, lng_f, lnb_f, bsage_f, bsg);
  k_count<<<(E + 255) / 256, 256, 0, stream>>>(dst, cnt, E);
  k_scan<<<1, 1024, 0, stream>>>(cnt, rowptr, cursor, N);
  k_perm<<<(E + 255) / 256, 256, 0, stream>>>(src, dst, cursor, src_sorted, E);
  int TT = (N + 15) / 16;
  int nb = (TT + 7) / 8;
  k_node<0><<<nb, 512, 0, stream>>>(flag, h, ctx, WmT, bm_f, lng_f, lnb_f, hm, N);
  k_node<1><<<nb, 512, 0, stream>>>(flag, h, ctx, WmT, bm_f, lng_f, lnb_f, hm, N);
  k_agg<<<2048, 256, 0, stream>>>(hm, rowptr, src_sorted, nm, cagg, N);
  k_out<0><<<512, 256, 0, stream>>>(flag, hm, nm, cagg, WsT, WnT, WsgT, WngT, WgBT,
                                    bsage_f, bsg, d_out, N);
  k_out<1><<<512, 256, 0, stream>>>(flag, hm, nm, cagg, WsT, WnT, WsgT, WngT, WgBT,
                                    bsage_f, bsg, d_out, N);
}

// Round 4
// 413.766 us; speedup vs baseline: 2.1016x; 1.4510x over previous
//
#include <hip/hip_runtime.h>

typedef unsigned short u16;
typedef unsigned int u32;
typedef __attribute__((ext_vector_type(8))) short sh8;
typedef __attribute__((ext_vector_type(4))) float f32x4;
typedef __attribute__((ext_vector_type(4))) unsigned short us4;

__device__ __forceinline__ float bf2f(u16 u) {
  union { u32 i; float f; } x; x.i = ((u32)u) << 16; return x.f;
}
__device__ __forceinline__ u16 f2bf(float f) {
  union { float f; u32 i; } x; x.f = f;
  u32 u = x.i;
  u32 r = (u + 0x7FFFu + ((u >> 16) & 1u)) >> 16;
  return (u16)r;
}

// External tensors are float32 (confirmed R2/R3: FETCH volumes + passing runs).
__device__ __forceinline__ sh8 load8f(const float* p, size_t off) {
  const float* f = p + off;
  f32x4 x = *(const f32x4*)f;
  f32x4 y = *(const f32x4*)(f + 4);
  sh8 r;
  r[0] = (short)f2bf(x[0]); r[1] = (short)f2bf(x[1]);
  r[2] = (short)f2bf(x[2]); r[3] = (short)f2bf(x[3]);
  r[4] = (short)f2bf(y[0]); r[5] = (short)f2bf(y[1]);
  r[6] = (short)f2bf(y[2]); r[7] = (short)f2bf(y[3]);
  return r;
}

// ---------------- prep: internal bf16 weights (transposed + fused) ----------
__global__ void k_prep(const float* __restrict__ Ws, const float* __restrict__ Wn,
                       const float* __restrict__ Wm, const float* __restrict__ Wg,
                       const float* __restrict__ b_sage, const float* __restrict__ bg,
                       const float* __restrict__ bm, const float* __restrict__ ln_g,
                       const float* __restrict__ ln_b,
                       u16* __restrict__ WmT, u16* __restrict__ WsT, u16* __restrict__ WnT,
                       u16* __restrict__ WsgT, u16* __restrict__ WngT, u16* __restrict__ WgBT,
                       float* __restrict__ bm_f, float* __restrict__ lng_f,
                       float* __restrict__ lnb_f, float* __restrict__ bsage_f,
                       float* __restrict__ bsg) {
  int idx = blockIdx.x * blockDim.x + threadIdx.x;
  int stride = gridDim.x * blockDim.x;
  for (int i = idx; i < 32768; i += stride) {
    int n = i >> 8, k = i & 255;
    WmT[n * 256 + k] = f2bf(Wm[k * 128 + n]);
  }
  for (int i = idx; i < 16384; i += stride) {
    int n = i >> 7, k = i & 127;
    WsT[i] = f2bf(Ws[k * 128 + n]);
    WnT[i] = f2bf(Wn[k * 128 + n]);
    WgBT[i] = f2bf(Wg[(128 + k) * 128 + n]);
  }
  for (int i = idx; i < 16384; i += stride) {
    int c = i >> 7, k = i & 127;
    float s1 = 0.f, s2 = 0.f;
    for (int j = 0; j < 128; ++j) {
      float wg = Wg[j * 128 + c];
      s1 += Ws[k * 128 + j] * wg;
      s2 += Wn[k * 128 + j] * wg;
    }
    WsgT[c * 128 + k] = f2bf(s1);
    WngT[c * 128 + k] = f2bf(s2);
  }
  for (int i = idx; i < 128; i += stride) {
    bm_f[i] = bm[i];
    lng_f[i] = ln_g[i];
    lnb_f[i] = ln_b[i];
    bsage_f[i] = b_sage[i];
    float s = bg[i];
    for (int j = 0; j < 128; ++j) s += b_sage[j] * Wg[j * 128 + i];
    bsg[i] = s;
  }
}

// ---------------- CSR build ----------------
__global__ void k_count(const int* __restrict__ dst, int* __restrict__ cnt, int E) {
  int e = blockIdx.x * blockDim.x + threadIdx.x;
  if (e < E) atomicAdd(&cnt[dst[e]], 1);
}

__global__ void k_scan(const int* __restrict__ cnt, int* __restrict__ rowptr,
                       int* __restrict__ cursor, int N) {
  __shared__ int sdata[1024];
  int t = threadIdx.x;
  int chunk = (N + 1023) >> 10;
  int beg = t * chunk;
  int end = min(beg + chunk, N);
  int s = 0;
  for (int i = beg; i < end; ++i) s += cnt[i];
  sdata[t] = s;
  __syncthreads();
  for (int off = 1; off < 1024; off <<= 1) {
    int v = (t >= off) ? sdata[t - off] : 0;
    __syncthreads();
    sdata[t] += v;
    __syncthreads();
  }
  int excl = sdata[t] - s;
  for (int i = beg; i < end; ++i) {
    rowptr[i] = excl;
    cursor[i] = excl;
    excl += cnt[i];
  }
  if (t == 1023) rowptr[N] = sdata[1023];
}

__global__ void k_perm(const int* __restrict__ src, const int* __restrict__ dst,
                       int* __restrict__ cursor, int* __restrict__ src_sorted, int E) {
  int e = blockIdx.x * blockDim.x + threadIdx.x;
  if (e < E) {
    int p = atomicAdd(&cursor[dst[e]], 1);
    src_sorted[p] = src[e];
  }
}

// ---------------- node MLP: M = relu(LN(concat(h,ctx)@Wm + bm)) -------------
// hm[n][0..127] = bf16(h[n]), hm[n][128..255] = M[n].
__global__ __launch_bounds__(512) void k_node(
    const float* __restrict__ h, const float* __restrict__ ctx,
    const u16* __restrict__ WmT, const float* __restrict__ bm_f,
    const float* __restrict__ lng_f, const float* __restrict__ lnb_f,
    u16* __restrict__ hm, int N) {
  __shared__ u16 wlds[128 * 256];  // 64 KB: WmT, XOR-swizzled 16B chunks
  int tid = threadIdx.x;
  for (int it = 0; it < 8; ++it) {
    int f = tid + it * 512;
    int n = f >> 5;
    int kc = f & 31;
    int kcs = kc ^ (n & 7);
    *(sh8*)&wlds[n * 256 + kcs * 8] = *(const sh8*)&WmT[n * 256 + kc * 8];
  }
  __syncthreads();
  int lane = tid & 63;
  int wave = tid >> 6;
  int col = lane & 15;
  int quad = lane >> 4;
  float bmv[8], gv[8], bv[8];
#pragma unroll
  for (int t = 0; t < 8; ++t) {
    int c = t * 16 + col;
    bmv[t] = bm_f[c];
    gv[t] = lng_f[c];
    bv[t] = lnb_f[c];
  }
  int totalWaves = gridDim.x * 8;
  int TT = (N + 15) >> 4;
  for (int tile = blockIdx.x * 8 + wave; tile < TT; tile += totalWaves) {
    int n0 = tile * 16;
    int m = min(n0 + col, N - 1);
    f32x4 acc[8];
    sh8 afrag[4];
#pragma unroll
    for (int t = 0; t < 8; ++t) acc[t] = (f32x4)0.0f;
#pragma unroll
    for (int ks = 0; ks < 8; ++ks) {
      int k = ks * 32 + quad * 8;
      sh8 a = (k < 128) ? load8f(h, (size_t)m * 128 + k)
                        : load8f(ctx, (size_t)m * 128 + k - 128);
      if (ks < 4) afrag[ks & 3] = a;
#pragma unroll
      for (int t = 0; t < 8; ++t) {
        int n = t * 16 + col;
        int kc = ks * 4 + quad;
        int kcs = kc ^ (n & 7);
        sh8 b = *(const sh8*)&wlds[n * 256 + kcs * 8];
        acc[t] = __builtin_amdgcn_mfma_f32_16x16x32_bf16(a, b, acc[t], 0, 0, 0);
      }
    }
#pragma unroll
    for (int ks = 0; ks < 4; ++ks)
      *(sh8*)&hm[(size_t)m * 256 + ks * 32 + quad * 8] = afrag[ks];
#pragma unroll
    for (int r = 0; r < 4; ++r) {
      float v[8];
      float s1 = 0.f, s2 = 0.f;
#pragma unroll
      for (int t = 0; t < 8; ++t) {
        v[t] = acc[t][r] + bmv[t];
        s1 += v[t];
        s2 += v[t] * v[t];
      }
#pragma unroll
      for (int mm = 1; mm < 16; mm <<= 1) {
        s1 += __shfl_xor(s1, mm, 64);
        s2 += __shfl_xor(s2, mm, 64);
      }
      float mu = s1 * (1.f / 128.f);
      float var = s2 * (1.f / 128.f) - mu * mu;
      float rstd = rsqrtf(fmaxf(var, 0.f) + 1e-5f);
      int row = n0 + quad * 4 + r;
      if (row < N) {
        u16* orow = hm + (size_t)row * 256 + 128;
#pragma unroll
        for (int t = 0; t < 8; ++t) {
          float x = (v[t] - mu) * rstd * gv[t] + bv[t];
          x = x > 0.f ? x : 0.f;
          orow[t * 16 + col] = f2bf(x);
        }
      }
    }
  }
}

// ---------------- per-node aggregation over hm rows -------------------------
__global__ __launch_bounds__(256) void k_agg(
    const u16* __restrict__ hm, const int* __restrict__ rowptr,
    const int* __restrict__ src_sorted,
    u16* __restrict__ nm, u16* __restrict__ cagg, int N) {
  int gw = (blockIdx.x * 256 + threadIdx.x) >> 6;
  int lane = threadIdx.x & 63;
  int tw = (gridDim.x * 256) >> 6;
  for (int n = gw; n < N; n += tw) {
    int b = rowptr[n], e = rowptr[n + 1];
    float s0 = 0.f, s1 = 0.f, s2 = 0.f, s3 = 0.f;
    int i = b;
    for (; i + 4 <= e; i += 4) {
      int e0 = src_sorted[i], e1 = src_sorted[i + 1];
      int e2 = src_sorted[i + 2], e3 = src_sorted[i + 3];
      us4 v0 = *(const us4*)(hm + (size_t)e0 * 256 + (lane << 2));
      us4 v1 = *(const us4*)(hm + (size_t)e1 * 256 + (lane << 2));
      us4 v2 = *(const us4*)(hm + (size_t)e2 * 256 + (lane << 2));
      us4 v3 = *(const us4*)(hm + (size_t)e3 * 256 + (lane << 2));
      s0 += bf2f(v0[0]) + bf2f(v1[0]) + bf2f(v2[0]) + bf2f(v3[0]);
      s1 += bf2f(v0[1]) + bf2f(v1[1]) + bf2f(v2[1]) + bf2f(v3[1]);
      s2 += bf2f(v0[2]) + bf2f(v1[2]) + bf2f(v2[2]) + bf2f(v3[2]);
      s3 += bf2f(v0[3]) + bf2f(v1[3]) + bf2f(v2[3]) + bf2f(v3[3]);
    }
    for (; i < e; ++i) {
      int e0 = src_sorted[i];
      us4 v0 = *(const us4*)(hm + (size_t)e0 * 256 + (lane << 2));
      s0 += bf2f(v0[0]);
      s1 += bf2f(v0[1]);
      s2 += bf2f(v0[2]);
      s3 += bf2f(v0[3]);
    }
    float inv = (e > b) ? 1.f / (float)(e - b) : 0.f;
    us4 p;
    p[0] = f2bf(s0 * inv); p[1] = f2bf(s1 * inv);
    p[2] = f2bf(s2 * inv); p[3] = f2bf(s3 * inv);
    if (lane < 32)
      *(us4*)(nm + (size_t)n * 128 + (lane << 2)) = p;
    else
      *(us4*)(cagg + (size_t)n * 128 + ((lane - 32) << 2)) = p;
  }
}

// ---------------- fused node GEMMs + gate + blend (col-split, LDS-B) --------
// Block owns 32 of 128 output cols; its B slice (5 mats x 32 cols x 128 K =
// 40 KB) is staged in LDS ONCE, then waves stride over 16-row tiles reading
// only A (hm/nm/cagg). Kills the per-tile 160 KB global B re-stream of R3.
__global__ __launch_bounds__(256) void k_out(
    const u16* __restrict__ hm, const u16* __restrict__ nm, const u16* __restrict__ cagg,
    const u16* __restrict__ WsT, const u16* __restrict__ WnT,
    const u16* __restrict__ WsgT, const u16* __restrict__ WngT, const u16* __restrict__ WgBT,
    const float* __restrict__ bsage_f, const float* __restrict__ bsg,
    float* __restrict__ out, int N) {
  __shared__ u16 blds[5 * 32 * 128];  // 40 KB
  int tid = threadIdx.x;
  int q = blockIdx.x & 3;  // column group: global cols q*32 .. q*32+31
  {
    const u16* matp[5] = {WsT, WnT, WsgT, WngT, WgBT};
#pragma unroll
    for (int m = 0; m < 5; ++m) {
#pragma unroll
      for (int j = 0; j < 2; ++j) {
        int f = tid + j * 256;  // 0..511 chunks of this mat
        int lc = f >> 4, kc = f & 15;
        int kcs = kc ^ (lc & 15);
        *(sh8*)&blds[(m * 32 + lc) * 128 + kcs * 8] =
            *(const sh8*)&matp[m][(size_t)(q * 32 + lc) * 128 + kc * 8];
      }
    }
  }
  __syncthreads();
  int lane = tid & 63;
  int wave = tid >> 6;
  int col = lane & 15, quad = lane >> 4;
  float bsv[2], bgv[2];
#pragma unroll
  for (int tt = 0; tt < 2; ++tt) {
    int gc = q * 32 + tt * 16 + col;
    bsv[tt] = bsage_f[gc];
    bgv[tt] = bsg[gc];
  }
  int TT = (N + 15) >> 4;
  int stride = gridDim.x;  // (gridDim.x>>2) row-streams * 4 waves
  for (int tile = (blockIdx.x >> 2) * 4 + wave; tile < TT; tile += stride) {
    int nr = min(tile * 16 + col, N - 1);
    sh8 ah[4], am[4], ac[4];
#pragma unroll
    for (int ks = 0; ks < 4; ++ks) {
      int k = ks * 32 + quad * 8;
      ah[ks] = *(const sh8*)&hm[(size_t)nr * 256 + k];
      am[ks] = *(const sh8*)&nm[(size_t)nr * 128 + k];
      ac[ks] = *(const sh8*)&cagg[(size_t)nr * 128 + k];
    }
    f32x4 as[2], ag[2];
#pragma unroll
    for (int tt = 0; tt < 2; ++tt) {
      as[tt] = (f32x4)0.0f;
      ag[tt] = (f32x4)0.0f;
    }
#pragma unroll
    for (int ks = 0; ks < 4; ++ks) {
      int kc = ks * 4 + quad;
      int kcs8 = (kc ^ col) * 8;
#pragma unroll
      for (int tt = 0; tt < 2; ++tt) {
        int lc = tt * 16 + col;
        sh8 b1 = *(const sh8*)&blds[(0 * 32 + lc) * 128 + kcs8];
        sh8 b2 = *(const sh8*)&blds[(1 * 32 + lc) * 128 + kcs8];
        sh8 b3 = *(const sh8*)&blds[(2 * 32 + lc) * 128 + kcs8];
        sh8 b4 = *(const sh8*)&blds[(3 * 32 + lc) * 128 + kcs8];
        sh8 b5 = *(const sh8*)&blds[(4 * 32 + lc) * 128 + kcs8];
        as[tt] = __builtin_amdgcn_mfma_f32_16x16x32_bf16(ah[ks], b1, as[tt], 0, 0, 0);
        as[tt] = __builtin_amdgcn_mfma_f32_16x16x32_bf16(am[ks], b2, as[tt], 0, 0, 0);
        ag[tt] = __builtin_amdgcn_mfma_f32_16x16x32_bf16(ah[ks], b3, ag[tt], 0, 0, 0);
        ag[tt] = __builtin_amdgcn_mfma_f32_16x16x32_bf16(am[ks], b4, ag[tt], 0, 0, 0);
        ag[tt] = __builtin_amdgcn_mfma_f32_16x16x32_bf16(ac[ks], b5, ag[tt], 0, 0, 0);
      }
    }
#pragma unroll
    for (int r = 0; r < 4; ++r) {
      int n = tile * 16 + quad * 4 + r;
      if (n < N) {
#pragma unroll
        for (int tt = 0; tt < 2; ++tt) {
          int gc = q * 32 + tt * 16 + col;
          float sv = as[tt][r] + bsv[tt];
          float gl = ag[tt][r] + bgv[tt];
          float g = 1.f / (1.f + __expf(-gl));
          float ca = bf2f(cagg[(size_t)n * 128 + gc]);
          out[(size_t)n * 128 + gc] = g * sv + (1.f - g) * ca;
        }
      }
    }
  }
}

extern "C" void kernel_launch(void* const* d_in, const int* in_sizes, int n_in,
                              void* d_out, int out_size, void* d_ws, size_t ws_size,
                              hipStream_t stream) {
  const float* h = (const float*)d_in[0];
  const float* ctx = (const float*)d_in[1];
  const int* src = (const int*)d_in[2];
  const int* dst = (const int*)d_in[3];
  const float* Ws = (const float*)d_in[4];
  const float* Wn = (const float*)d_in[5];
  const float* b_sage = (const float*)d_in[6];
  const float* Wm = (const float*)d_in[7];
  const float* bm = (const float*)d_in[8];
  const float* ln_g = (const float*)d_in[9];
  const float* ln_b = (const float*)d_in[10];
  const float* Wg = (const float*)d_in[11];
  const float* bg = (const float*)d_in[12];
  int N = in_sizes[0] / 128;
  int E = in_sizes[2];

  char* w = (char*)d_ws;
  auto carve = [&](size_t bytes) {
    char* p = w;
    w += (bytes + 255) & ~(size_t)255;
    return p;
  };
  int* cnt = (int*)carve((size_t)N * 4);
  int* rowptr = (int*)carve((size_t)(N + 1) * 4);
  int* cursor = (int*)carve((size_t)N * 4);
  int* src_sorted = (int*)carve((size_t)E * 4);
  u16* WmT = (u16*)carve(32768 * 2);
  u16* WsT = (u16*)carve(16384 * 2);
  u16* WnT = (u16*)carve(16384 * 2);
  u16* WsgT = (u16*)carve(16384 * 2);
  u16* WngT = (u16*)carve(16384 * 2);
  u16* WgBT = (u16*)carve(16384 * 2);
  float* bm_f = (float*)carve(128 * 4);
  float* lng_f = (float*)carve(128 * 4);
  float* lnb_f = (float*)carve(128 * 4);
  float* bsage_f = (float*)carve(128 * 4);
  float* bsg = (float*)carve(128 * 4);
  u16* hm = (u16*)carve((size_t)N * 256 * 2);
  u16* nm = (u16*)carve((size_t)N * 128 * 2);
  u16* cagg = (u16*)carve((size_t)N * 128 * 2);

  hipMemsetAsync(cnt, 0, (size_t)N * 4, stream);
  k_prep<<<128, 256, 0, stream>>>(Ws, Wn, Wm, Wg, b_sage, bg, bm, ln_g, ln_b,
                                  WmT, WsT, WnT, WsgT, WngT, WgBT,
                                  bm_f, lng_f, lnb_f, bsage_f, bsg);
  k_count<<<(E + 255) / 256, 256, 0, stream>>>(dst, cnt, E);
  k_scan<<<1, 1024, 0, stream>>>(cnt, rowptr, cursor, N);
  k_perm<<<(E + 255) / 256, 256, 0, stream>>>(src, dst, cursor, src_sorted, E);
  int TT = (N + 15) / 16;
  int nb = (TT + 7) / 8;
  k_node<<<nb, 512, 0, stream>>>(h, ctx, WmT, bm_f, lng_f, lnb_f, hm, N);
  k_agg<<<2048, 256, 0, stream>>>(hm, rowptr, src_sorted, nm, cagg, N);
  k_out<<<1024, 256, 0, stream>>>(hm, nm, cagg, WsT, WnT, WsgT, WngT, WgBT,
                                  bsage_f, bsg, (float*)d_out, N);
}

// Round 5
// 314.707 us; speedup vs baseline: 2.7631x; 1.3148x over previous
//
#include <hip/hip_runtime.h>

typedef unsigned short u16;
typedef unsigned int u32;
typedef __attribute__((ext_vector_type(8))) short sh8;
typedef __attribute__((ext_vector_type(4))) float f32x4;
typedef __attribute__((ext_vector_type(4))) unsigned short us4;

__device__ __forceinline__ float bf2f(u16 u) {
  union { u32 i; float f; } x; x.i = ((u32)u) << 16; return x.f;
}
__device__ __forceinline__ u16 f2bf(float f) {
  union { float f; u32 i; } x; x.f = f;
  u32 u = x.i;
  u32 r = (u + 0x7FFFu + ((u >> 16) & 1u)) >> 16;
  return (u16)r;
}

// External tensors are float32 (confirmed R2/R3: FETCH volumes + passing runs).
__device__ __forceinline__ sh8 load8f(const float* p, size_t off) {
  const float* f = p + off;
  f32x4 x = *(const f32x4*)f;
  f32x4 y = *(const f32x4*)(f + 4);
  sh8 r;
  r[0] = (short)f2bf(x[0]); r[1] = (short)f2bf(x[1]);
  r[2] = (short)f2bf(x[2]); r[3] = (short)f2bf(x[3]);
  r[4] = (short)f2bf(y[0]); r[5] = (short)f2bf(y[1]);
  r[6] = (short)f2bf(y[2]); r[7] = (short)f2bf(y[3]);
  return r;
}

// ---------------- prep: internal bf16 weights (transposed + fused) ----------
__global__ void k_prep(const float* __restrict__ Ws, const float* __restrict__ Wn,
                       const float* __restrict__ Wm, const float* __restrict__ Wg,
                       const float* __restrict__ b_sage, const float* __restrict__ bg,
                       const float* __restrict__ bm, const float* __restrict__ ln_g,
                       const float* __restrict__ ln_b,
                       u16* __restrict__ WmT, u16* __restrict__ WsT, u16* __restrict__ WnT,
                       u16* __restrict__ WsgT, u16* __restrict__ WngT, u16* __restrict__ WgBT,
                       float* __restrict__ bm_f, float* __restrict__ lng_f,
                       float* __restrict__ lnb_f, float* __restrict__ bsage_f,
                       float* __restrict__ bsg) {
  int idx = blockIdx.x * blockDim.x + threadIdx.x;
  int stride = gridDim.x * blockDim.x;
  for (int i = idx; i < 32768; i += stride) {
    int n = i >> 8, k = i & 255;
    WmT[n * 256 + k] = f2bf(Wm[k * 128 + n]);
  }
  for (int i = idx; i < 16384; i += stride) {
    int n = i >> 7, k = i & 127;
    WsT[i] = f2bf(Ws[k * 128 + n]);
    WnT[i] = f2bf(Wn[k * 128 + n]);
    WgBT[i] = f2bf(Wg[(128 + k) * 128 + n]);
  }
  for (int i = idx; i < 16384; i += stride) {
    int c = i >> 7, k = i & 127;
    float s1 = 0.f, s2 = 0.f;
    for (int j = 0; j < 128; ++j) {
      float wg = Wg[j * 128 + c];
      s1 += Ws[k * 128 + j] * wg;
      s2 += Wn[k * 128 + j] * wg;
    }
    WsgT[c * 128 + k] = f2bf(s1);
    WngT[c * 128 + k] = f2bf(s2);
  }
  for (int i = idx; i < 128; i += stride) {
    bm_f[i] = bm[i];
    lng_f[i] = ln_g[i];
    lnb_f[i] = ln_b[i];
    bsage_f[i] = b_sage[i];
    float s = bg[i];
    for (int j = 0; j < 128; ++j) s += b_sage[j] * Wg[j * 128 + i];
    bsg[i] = s;
  }
}

// ---------------- CSR build ----------------
__global__ void k_count(const int* __restrict__ dst, int* __restrict__ cnt, int E) {
  int e = blockIdx.x * blockDim.x + threadIdx.x;
  if (e < E) atomicAdd(&cnt[dst[e]], 1);
}

// 3-phase parallel exclusive scan (R4: single-block scan was 111us, 1 CU).
__global__ void k_scan1(const int* __restrict__ cnt, int* __restrict__ bsum, int N) {
  int i = blockIdx.x * 256 + threadIdx.x;
  int v = (i < N) ? cnt[i] : 0;
#pragma unroll
  for (int m = 1; m < 64; m <<= 1) v += __shfl_xor(v, m, 64);
  __shared__ int ws[4];
  if ((threadIdx.x & 63) == 0) ws[threadIdx.x >> 6] = v;
  __syncthreads();
  if (threadIdx.x == 0) bsum[blockIdx.x] = ws[0] + ws[1] + ws[2] + ws[3];
}

__global__ void k_scan2(const int* __restrict__ bsum, int* __restrict__ boff, int NB) {
  __shared__ int s[256];
  int t = threadIdx.x;
  int v = (t < NB) ? bsum[t] : 0;
  s[t] = v;
  __syncthreads();
  for (int off = 1; off < 256; off <<= 1) {
    int x = (t >= off) ? s[t - off] : 0;
    __syncthreads();
    s[t] += x;
    __syncthreads();
  }
  if (t < NB) boff[t] = s[t] - v;
}

__global__ void k_scan3(const int* __restrict__ cnt, const int* __restrict__ boff,
                        int* __restrict__ rowptr, int* __restrict__ cursor, int N) {
  __shared__ int s[256];
  int t = threadIdx.x;
  int i = blockIdx.x * 256 + t;
  int v = (i < N) ? cnt[i] : 0;
  s[t] = v;
  __syncthreads();
  for (int off = 1; off < 256; off <<= 1) {
    int x = (t >= off) ? s[t - off] : 0;
    __syncthreads();
    s[t] += x;
    __syncthreads();
  }
  int excl = boff[blockIdx.x] + s[t] - v;
  if (i < N) {
    rowptr[i] = excl;
    cursor[i] = excl;
    if (i == N - 1) rowptr[N] = excl + v;
  }
}

__global__ void k_perm(const int* __restrict__ src, const int* __restrict__ dst,
                       int* __restrict__ cursor, int* __restrict__ src_sorted, int E) {
  int e = blockIdx.x * blockDim.x + threadIdx.x;
  if (e < E) {
    int p = atomicAdd(&cursor[dst[e]], 1);
    src_sorted[p] = src[e];
  }
}

// ---------------- node MLP: M = relu(LN(concat(h,ctx)@Wm + bm)) -------------
// hm[n][0..127] = bf16(h[n]), hm[n][128..255] = M[n].
__global__ __launch_bounds__(512) void k_node(
    const float* __restrict__ h, const float* __restrict__ ctx,
    const u16* __restrict__ WmT, const float* __restrict__ bm_f,
    const float* __restrict__ lng_f, const float* __restrict__ lnb_f,
    u16* __restrict__ hm, int N) {
  __shared__ u16 wlds[128 * 256];  // 64 KB: WmT, XOR-swizzled 16B chunks
  int tid = threadIdx.x;
  for (int it = 0; it < 8; ++it) {
    int f = tid + it * 512;
    int n = f >> 5;
    int kc = f & 31;
    int kcs = kc ^ (n & 7);
    *(sh8*)&wlds[n * 256 + kcs * 8] = *(const sh8*)&WmT[n * 256 + kc * 8];
  }
  __syncthreads();
  int lane = tid & 63;
  int wave = tid >> 6;
  int col = lane & 15;
  int quad = lane >> 4;
  float bmv[8], gv[8], bv[8];
#pragma unroll
  for (int t = 0; t < 8; ++t) {
    int c = t * 16 + col;
    bmv[t] = bm_f[c];
    gv[t] = lng_f[c];
    bv[t] = lnb_f[c];
  }
  int totalWaves = gridDim.x * 8;
  int TT = (N + 15) >> 4;
  for (int tile = blockIdx.x * 8 + wave; tile < TT; tile += totalWaves) {
    int n0 = tile * 16;
    int m = min(n0 + col, N - 1);
    f32x4 acc[8];
    sh8 afrag[4];
#pragma unroll
    for (int t = 0; t < 8; ++t) acc[t] = (f32x4)0.0f;
#pragma unroll
    for (int ks = 0; ks < 8; ++ks) {
      int k = ks * 32 + quad * 8;
      sh8 a = (k < 128) ? load8f(h, (size_t)m * 128 + k)
                        : load8f(ctx, (size_t)m * 128 + k - 128);
      if (ks < 4) afrag[ks & 3] = a;
#pragma unroll
      for (int t = 0; t < 8; ++t) {
        int n = t * 16 + col;
        int kc = ks * 4 + quad;
        int kcs = kc ^ (n & 7);
        sh8 b = *(const sh8*)&wlds[n * 256 + kcs * 8];
        acc[t] = __builtin_amdgcn_mfma_f32_16x16x32_bf16(a, b, acc[t], 0, 0, 0);
      }
    }
#pragma unroll
    for (int ks = 0; ks < 4; ++ks)
      *(sh8*)&hm[(size_t)m * 256 + ks * 32 + quad * 8] = afrag[ks];
#pragma unroll
    for (int r = 0; r < 4; ++r) {
      float v[8];
      float s1 = 0.f, s2 = 0.f;
#pragma unroll
      for (int t = 0; t < 8; ++t) {
        v[t] = acc[t][r] + bmv[t];
        s1 += v[t];
        s2 += v[t] * v[t];
      }
#pragma unroll
      for (int mm = 1; mm < 16; mm <<= 1) {
        s1 += __shfl_xor(s1, mm, 64);
        s2 += __shfl_xor(s2, mm, 64);
      }
      float mu = s1 * (1.f / 128.f);
      float var = s2 * (1.f / 128.f) - mu * mu;
      float rstd = rsqrtf(fmaxf(var, 0.f) + 1e-5f);
      int row = n0 + quad * 4 + r;
      if (row < N) {
        u16* orow = hm + (size_t)row * 256 + 128;
#pragma unroll
        for (int t = 0; t < 8; ++t) {
          float x = (v[t] - mu) * rstd * gv[t] + bv[t];
          x = x > 0.f ? x : 0.f;
          orow[t * 16 + col] = f2bf(x);
        }
      }
    }
  }
}

// ---------------- per-node aggregation over hm rows -------------------------
__global__ __launch_bounds__(256) void k_agg(
    const u16* __restrict__ hm, const int* __restrict__ rowptr,
    const int* __restrict__ src_sorted,
    u16* __restrict__ nm, u16* __restrict__ cagg, int N) {
  int gw = (blockIdx.x * 256 + threadIdx.x) >> 6;
  int lane = threadIdx.x & 63;
  int tw = (gridDim.x * 256) >> 6;
  for (int n = gw; n < N; n += tw) {
    int b = rowptr[n], e = rowptr[n + 1];
    float s0 = 0.f, s1 = 0.f, s2 = 0.f, s3 = 0.f;
    int i = b;
    for (; i + 4 <= e; i += 4) {
      int e0 = src_sorted[i], e1 = src_sorted[i + 1];
      int e2 = src_sorted[i + 2], e3 = src_sorted[i + 3];
      us4 v0 = *(const us4*)(hm + (size_t)e0 * 256 + (lane << 2));
      us4 v1 = *(const us4*)(hm + (size_t)e1 * 256 + (lane << 2));
      us4 v2 = *(const us4*)(hm + (size_t)e2 * 256 + (lane << 2));
      us4 v3 = *(const us4*)(hm + (size_t)e3 * 256 + (lane << 2));
      s0 += bf2f(v0[0]) + bf2f(v1[0]) + bf2f(v2[0]) + bf2f(v3[0]);
      s1 += bf2f(v0[1]) + bf2f(v1[1]) + bf2f(v2[1]) + bf2f(v3[1]);
      s2 += bf2f(v0[2]) + bf2f(v1[2]) + bf2f(v2[2]) + bf2f(v3[2]);
      s3 += bf2f(v0[3]) + bf2f(v1[3]) + bf2f(v2[3]) + bf2f(v3[3]);
    }
    for (; i < e; ++i) {
      int e0 = src_sorted[i];
      us4 v0 = *(const us4*)(hm + (size_t)e0 * 256 + (lane << 2));
      s0 += bf2f(v0[0]);
      s1 += bf2f(v0[1]);
      s2 += bf2f(v0[2]);
      s3 += bf2f(v0[3]);
    }
    float inv = (e > b) ? 1.f / (float)(e - b) : 0.f;
    us4 p;
    p[0] = f2bf(s0 * inv); p[1] = f2bf(s1 * inv);
    p[2] = f2bf(s2 * inv); p[3] = f2bf(s3 * inv);
    if (lane < 32)
      *(us4*)(nm + (size_t)n * 128 + (lane << 2)) = p;
    else
      *(us4*)(cagg + (size_t)n * 128 + ((lane - 32) << 2)) = p;
  }
}

// ---------------- fused node GEMMs + gate + blend (col-split, LDS-B) --------
__global__ __launch_bounds__(256) void k_out(
    const u16* __restrict__ hm, const u16* __restrict__ nm, const u16* __restrict__ cagg,
    const u16* __restrict__ WsT, const u16* __restrict__ WnT,
    const u16* __restrict__ WsgT, const u16* __restrict__ WngT, const u16* __restrict__ WgBT,
    const float* __restrict__ bsage_f, const float* __restrict__ bsg,
    float* __restrict__ out, int N) {
  __shared__ u16 blds[5 * 32 * 128];  // 40 KB
  int tid = threadIdx.x;
  int q = blockIdx.x & 3;  // column group: global cols q*32 .. q*32+31
  {
    const u16* matp[5] = {WsT, WnT, WsgT, WngT, WgBT};
#pragma unroll
    for (int m = 0; m < 5; ++m) {
#pragma unroll
      for (int j = 0; j < 2; ++j) {
        int f = tid + j * 256;
        int lc = f >> 4, kc = f & 15;
        int kcs = kc ^ (lc & 15);
        *(sh8*)&blds[(m * 32 + lc) * 128 + kcs * 8] =
            *(const sh8*)&matp[m][(size_t)(q * 32 + lc) * 128 + kc * 8];
      }
    }
  }
  __syncthreads();
  int lane = tid & 63;
  int wave = tid >> 6;
  int col = lane & 15, quad = lane >> 4;
  float bsv[2], bgv[2];
#pragma unroll
  for (int tt = 0; tt < 2; ++tt) {
    int gc = q * 32 + tt * 16 + col;
    bsv[tt] = bsage_f[gc];
    bgv[tt] = bsg[gc];
  }
  int TT = (N + 15) >> 4;
  int stride = gridDim.x;
  for (int tile = (blockIdx.x >> 2) * 4 + wave; tile < TT; tile += stride) {
    int nr = min(tile * 16 + col, N - 1);
    sh8 ah[4], am[4], ac[4];
#pragma unroll
    for (int ks = 0; ks < 4; ++ks) {
      int k = ks * 32 + quad * 8;
      ah[ks] = *(const sh8*)&hm[(size_t)nr * 256 + k];
      am[ks] = *(const sh8*)&nm[(size_t)nr * 128 + k];
      ac[ks] = *(const sh8*)&cagg[(size_t)nr * 128 + k];
    }
    f32x4 as[2], ag[2];
#pragma unroll
    for (int tt = 0; tt < 2; ++tt) {
      as[tt] = (f32x4)0.0f;
      ag[tt] = (f32x4)0.0f;
    }
#pragma unroll
    for (int ks = 0; ks < 4; ++ks) {
      int kc = ks * 4 + quad;
      int kcs8 = (kc ^ col) * 8;
#pragma unroll
      for (int tt = 0; tt < 2; ++tt) {
        int lc = tt * 16 + col;
        sh8 b1 = *(const sh8*)&blds[(0 * 32 + lc) * 128 + kcs8];
        sh8 b2 = *(const sh8*)&blds[(1 * 32 + lc) * 128 + kcs8];
        sh8 b3 = *(const sh8*)&blds[(2 * 32 + lc) * 128 + kcs8];
        sh8 b4 = *(const sh8*)&blds[(3 * 32 + lc) * 128 + kcs8];
        sh8 b5 = *(const sh8*)&blds[(4 * 32 + lc) * 128 + kcs8];
        as[tt] = __builtin_amdgcn_mfma_f32_16x16x32_bf16(ah[ks], b1, as[tt], 0, 0, 0);
        as[tt] = __builtin_amdgcn_mfma_f32_16x16x32_bf16(am[ks], b2, as[tt], 0, 0, 0);
        ag[tt] = __builtin_amdgcn_mfma_f32_16x16x32_bf16(ah[ks], b3, ag[tt], 0, 0, 0);
        ag[tt] = __builtin_amdgcn_mfma_f32_16x16x32_bf16(am[ks], b4, ag[tt], 0, 0, 0);
        ag[tt] = __builtin_amdgcn_mfma_f32_16x16x32_bf16(ac[ks], b5, ag[tt], 0, 0, 0);
      }
    }
#pragma unroll
    for (int r = 0; r < 4; ++r) {
      int n = tile * 16 + quad * 4 + r;
      if (n < N) {
#pragma unroll
        for (int tt = 0; tt < 2; ++tt) {
          int gc = q * 32 + tt * 16 + col;
          float sv = as[tt][r] + bsv[tt];
          float gl = ag[tt][r] + bgv[tt];
          float g = 1.f / (1.f + __expf(-gl));
          float ca = bf2f(cagg[(size_t)n * 128 + gc]);
          out[(size_t)n * 128 + gc] = g * sv + (1.f - g) * ca;
        }
      }
    }
  }
}

extern "C" void kernel_launch(void* const* d_in, const int* in_sizes, int n_in,
                              void* d_out, int out_size, void* d_ws, size_t ws_size,
                              hipStream_t stream) {
  const float* h = (const float*)d_in[0];
  const float* ctx = (const float*)d_in[1];
  const int* src = (const int*)d_in[2];
  const int* dst = (const int*)d_in[3];
  const float* Ws = (const float*)d_in[4];
  const float* Wn = (const float*)d_in[5];
  const float* b_sage = (const float*)d_in[6];
  const float* Wm = (const float*)d_in[7];
  const float* bm = (const float*)d_in[8];
  const float* ln_g = (const float*)d_in[9];
  const float* ln_b = (const float*)d_in[10];
  const float* Wg = (const float*)d_in[11];
  const float* bg = (const float*)d_in[12];
  int N = in_sizes[0] / 128;
  int E = in_sizes[2];

  char* w = (char*)d_ws;
  auto carve = [&](size_t bytes) {
    char* p = w;
    w += (bytes + 255) & ~(size_t)255;
    return p;
  };
  int* cnt = (int*)carve((size_t)N * 4);
  int* rowptr = (int*)carve((size_t)(N + 1) * 4);
  int* cursor = (int*)carve((size_t)N * 4);
  int* src_sorted = (int*)carve((size_t)E * 4);
  int NB = (N + 255) / 256;
  int* bsum = (int*)carve((size_t)NB * 4);
  int* boff = (int*)carve((size_t)NB * 4);
  u16* WmT = (u16*)carve(32768 * 2);
  u16* WsT = (u16*)carve(16384 * 2);
  u16* WnT = (u16*)carve(16384 * 2);
  u16* WsgT = (u16*)carve(16384 * 2);
  u16* WngT = (u16*)carve(16384 * 2);
  u16* WgBT = (u16*)carve(16384 * 2);
  float* bm_f = (float*)carve(128 * 4);
  float* lng_f = (float*)carve(128 * 4);
  float* lnb_f = (float*)carve(128 * 4);
  float* bsage_f = (float*)carve(128 * 4);
  float* bsg = (float*)carve(128 * 4);
  u16* hm = (u16*)carve((size_t)N * 256 * 2);
  u16* nm = (u16*)carve((size_t)N * 128 * 2);
  u16* cagg = (u16*)carve((size_t)N * 128 * 2);

  hipMemsetAsync(cnt, 0, (size_t)N * 4, stream);
  k_prep<<<128, 256, 0, stream>>>(Ws, Wn, Wm, Wg, b_sage, bg, bm, ln_g, ln_b,
                                  WmT, WsT, WnT, WsgT, WngT, WgBT,
                                  bm_f, lng_f, lnb_f, bsage_f, bsg);
  k_count<<<(E + 255) / 256, 256, 0, stream>>>(dst, cnt, E);
  k_scan1<<<NB, 256, 0, stream>>>(cnt, bsum, N);
  k_scan2<<<1, 256, 0, stream>>>(bsum, boff, NB);
  k_scan3<<<NB, 256, 0, stream>>>(cnt, boff, rowptr, cursor, N);
  k_perm<<<(E + 255) / 256, 256, 0, stream>>>(src, dst, cursor, src_sorted, E);
  int TT = (N + 15) / 16;
  int nb = (TT + 7) / 8;
  k_node<<<nb, 512, 0, stream>>>(h, ctx, WmT, bm_f, lng_f, lnb_f, hm, N);
  k_agg<<<2048, 256, 0, stream>>>(hm, rowptr, src_sorted, nm, cagg, N);
  k_out<<<1024, 256, 0, stream>>>(hm, nm, cagg, WsT, WnT, WsgT, WngT, WgBT,
                                  bsage_f, bsg, (float*)d_out, N);
}